// Round 4
// baseline (2816.624 us; speedup 1.0000x reference)
//
#include <hip/hip_runtime.h>

typedef _Float16 h8 __attribute__((ext_vector_type(8)));
typedef _Float16 hv4 __attribute__((ext_vector_type(4)));
typedef float f4 __attribute__((ext_vector_type(4)));

#define SEQ_LEN 50
#define HID 64
#define HSTRIDE 76  // halves; 152B row pitch -> conflict-free b64 A-frag reads

#if __has_builtin(__builtin_amdgcn_exp2f)
#define EXP2(x) __builtin_amdgcn_exp2f(x)
#else
extern "C" __device__ float __ocml_native_exp2_f32(float);
#define EXP2(x) __ocml_native_exp2_f32(x)
#endif
#define RCP(x) __builtin_amdgcn_rcpf(x)

#define LOG2E 1.442695041f

// exp-path sigmoid, input pre-scaled by log2e: sigmoid(v/log2e) = 1/(1+2^-v)
// cost: 2 trans + 1 VALU
__device__ __forceinline__ float sig2(float v) {
    return RCP(1.0f + EXP2(-v));
}
// Pade[7/6] tanh (Lambert continued fraction), clamp +/-4.75.
// err <= ~2.4e-4 at clamp; tanh(4.75)=0.99985 -> tail err 1.5e-4.
// cost: 1 trans + ~11 VALU  (moves load off the 16-cyc trans pipe)
__device__ __forceinline__ float ptanh(float t) {
    t = fminf(fmaxf(t, -4.75f), 4.75f);
    float s = t * t;
    float num = t * fmaf(s, fmaf(s, (s + 378.0f), 17325.0f), 135135.0f);
    float den = fmaf(s, fmaf(s, fmaf(s, 28.0f, 3150.0f), 62370.0f), 135135.0f);
    return num * RCP(den);
}
// poly sigmoid via tanh: sigma(x) = 0.5 + 0.5*tanh(x/2)
__device__ __forceinline__ float psig(float x) {
    return fmaf(ptanh(0.5f * x), 0.5f, 0.5f);
}

// Block = 128 threads = 2 waves, owns 16 sequences.
// Wave w computes n-tiles {g*4 + 2w + d : g in 0..3 (i,f,g,o), d in 0..1}.
// C-layout (16x16x32): col = lane&15 (seq... n within tile), row = quad*4+reg.
// Register budget: combined VGPR+AGPR demand ~170-256 -> ONLY 2 waves/SIMD
// fit without spilling. (128,4) spilled 24 GB (R2); (128,3) spilled 3 GB (R3).
__global__ __launch_bounds__(128, 2)
void lstm_fused(const float* __restrict__ x,
                const float* __restrict__ W_ih,
                const float* __restrict__ W_hh,
                const float* __restrict__ b_ih,
                const float* __restrict__ b_hh,
                const float* __restrict__ W_fc,
                const float* __restrict__ b_fc,
                float* __restrict__ out)
{
    __shared__ _Float16 sH[2][16 * HSTRIDE];  // h double-buffer, fp16
    __shared__ float    sXT[SEQ_LEN * 16];    // x tile, TRANSPOSED [t][seq]

    const int tid  = threadIdx.x;
    const int wave = tid >> 6;
    const int lane = tid & 63;
    const int col  = lane & 15;
    const int quad = lane >> 4;
    const int seqBase = blockIdx.x << 4;

    // ---- stage x transposed: sXT[t*16 + s] = x[(seqBase+s)*50 + t]
    for (int i = tid; i < SEQ_LEN * 16; i += 128) {
        const int s = i & 15;
        const int t = i >> 4;
        sXT[t * 16 + s] = x[(size_t)(seqBase + s) * SEQ_LEN + t];
    }
    // ---- zero both h buffers (h0 = 0)
    for (int i = tid; i < 2 * 16 * HSTRIDE; i += 128)
        ((_Float16*)sH)[i] = (_Float16)0.0f;

    // ---- W_hh as resident fp16 B-fragments.
    // i/f gate rows pre-scaled by log2e (exp2-path sigmoid, no mul needed);
    // g/o gate rows UNSCALED (poly-path tanh/sigmoid).
    h8 Bf[8][2];
    float wih[8], bs[8];
    #pragma unroll
    for (int g = 0; g < 4; ++g) {
        const float scale = (g < 2) ? LOG2E : 1.0f;
        #pragma unroll
        for (int d = 0; d < 2; ++d) {
            const int tt = g * 2 + d;
            const int n  = (g * 4 + 2 * wave + d) * 16 + col;
            wih[tt] = W_ih[n] * scale;
            bs[tt]  = (b_ih[n] + b_hh[n]) * scale;
            #pragma unroll
            for (int kf = 0; kf < 2; ++kf) {
                const float* wp = W_hh + n * HID + kf * 32 + quad * 8;
                f4 lo = *(const f4*)wp;
                f4 hi = *(const f4*)(wp + 4);
                h8 b;
                b[0] = (_Float16)(lo[0] * scale); b[1] = (_Float16)(lo[1] * scale);
                b[2] = (_Float16)(lo[2] * scale); b[3] = (_Float16)(lo[3] * scale);
                b[4] = (_Float16)(hi[0] * scale); b[5] = (_Float16)(hi[1] * scale);
                b[6] = (_Float16)(hi[2] * scale); b[7] = (_Float16)(hi[3] * scale);
                Bf[tt][kf] = b;
            }
        }
    }

    // cell state, plain domain
    float c[2][4];
    #pragma unroll
    for (int d = 0; d < 2; ++d)
        #pragma unroll
        for (int r = 0; r < 4; ++r) c[d][r] = 0.0f;

    __syncthreads();

    #pragma unroll 2
    for (int t = 0; t < SEQ_LEN; ++t) {
        const _Float16* hb = sH[t & 1];
        _Float16*       hw = sH[(t + 1) & 1];

        // x_t for this lane's 4 rows: one broadcast ds_read_b128
        const f4 xq = *(const f4*)(sXT + t * 16 + quad * 4);

        // A-fragments of current h (two b64 reads each; 152B pitch, no conflicts)
        h8 A[2];
        #pragma unroll
        for (int kf = 0; kf < 2; ++kf) {
            const _Float16* p = hb + col * HSTRIDE + kf * 32 + quad * 8;
            hv4 a0 = *(const hv4*)p;
            hv4 a1 = *(const hv4*)(p + 4);
            A[kf] = __builtin_shufflevector(a0, a1, 0, 1, 2, 3, 4, 5, 6, 7);
        }

        // Two groups of 4 tiles (d = 0,1): 4 live accumulators each;
        // group-0 activations overlap group-1 MFMAs.
        #pragma unroll
        for (int d = 0; d < 2; ++d) {
            f4 acc[4];
            #pragma unroll
            for (int g4 = 0; g4 < 4; ++g4) {
                const int tt = g4 * 2 + d;
                f4 a;
                #pragma unroll
                for (int r = 0; r < 4; ++r) a[r] = fmaf(xq[r], wih[tt], bs[tt]);
                a = __builtin_amdgcn_mfma_f32_16x16x32_f16(A[0], Bf[tt][0], a, 0, 0, 0);
                a = __builtin_amdgcn_mfma_f32_16x16x32_f16(A[1], Bf[tt][1], a, 0, 0, 0);
                acc[g4] = a;
            }
            // activations: i,f on trans pipe (exp2); g,o and c-tanh on VALU
            // pipe (Pade) -> trans/VALU balanced ~896 vs ~780 cyc/wave-step.
            #pragma unroll
            for (int r = 0; r < 4; ++r) {
                float ig = sig2(acc[0][r]);     // input pre-scaled log2e
                float fg = sig2(acc[1][r]);     // input pre-scaled log2e
                float gg = ptanh(acc[2][r]);    // unscaled
                float og = psig(acc[3][r]);     // unscaled
                float cc = fmaf(fg, c[d][r], ig * gg);
                c[d][r] = cc;
                float hh = og * ptanh(cc);
                hw[(quad * 4 + r) * HSTRIDE + 32 * wave + d * 16 + col] = (_Float16)hh;
            }
        }
        __syncthreads();
    }

    // ---- epilogue: final h is in sH[0] (t=49 wrote buffer (49+1)&1 = 0)
    if (lane < 24) {
        const int sl = wave * 8 + lane / 3;  // sequence within tile
        const int nc = lane % 3;             // class
        const _Float16* hp = sH[0] + sl * HSTRIDE;
        float a = b_fc[nc];
        #pragma unroll
        for (int u = 0; u < HID; ++u)
            a = fmaf((float)hp[u], W_fc[nc * HID + u], a);
        out[(size_t)(seqBase + sl) * 3 + nc] = a;
    }
}

extern "C" void kernel_launch(void* const* d_in, const int* in_sizes, int n_in,
                              void* d_out, int out_size, void* d_ws, size_t ws_size,
                              hipStream_t stream) {
    const float* x    = (const float*)d_in[0];
    const float* W_ih = (const float*)d_in[1];
    const float* W_hh = (const float*)d_in[2];
    const float* b_ih = (const float*)d_in[3];
    const float* b_hh = (const float*)d_in[4];
    const float* W_fc = (const float*)d_in[5];
    const float* b_fc = (const float*)d_in[6];
    float* out = (float*)d_out;

    const int nSeq   = in_sizes[0] / SEQ_LEN;  // 512000
    const int blocks = nSeq / 16;              // 32000

    hipLaunchKernelGGL(lstm_fused, dim3(blocks), dim3(128), 0, stream,
                       x, W_ih, W_hh, b_ih, b_hh, W_fc, b_fc, out);
}

// Round 5
// 1827.419 us; speedup vs baseline: 1.5413x; 1.5413x over previous
//
#include <hip/hip_runtime.h>

typedef _Float16 h8 __attribute__((ext_vector_type(8)));
typedef _Float16 h4 __attribute__((ext_vector_type(4)));
typedef float f4 __attribute__((ext_vector_type(4)));

#define SEQ_LEN 50
#define HID 64
#define HS 72  // halves per h row: 144B pitch; 16B-aligned b128 reads, 2-way max within quad-phase

#if __has_builtin(__builtin_amdgcn_exp2f)
#define EXP2(x) __builtin_amdgcn_exp2f(x)
#else
extern "C" __device__ float __ocml_native_exp2_f32(float);
#define EXP2(x) __ocml_native_exp2_f32(x)
#endif
#define RCP(x) __builtin_amdgcn_rcpf(x)

#define LOG2E  1.442695041f
#define LOG2E2 2.885390082f

// input pre-scaled by log2e: sigmoid(v/log2e) = 1/(1+2^-v)          [3 issues]
__device__ __forceinline__ float sig2(float v)   { return RCP(1.0f + EXP2(-v)); }
// input pre-scaled by 2log2e: LOG2E2*tanh(v/(2log2e)) (scaled cell) [4 issues]
__device__ __forceinline__ float tanh2s(float v) { return fmaf(RCP(1.0f + EXP2(v)), -2.0f*LOG2E2, LOG2E2); }
// input pre-scaled by 2log2e: tanh(v/(2log2e))                      [4 issues]
__device__ __forceinline__ float tanh2(float v)  { return 1.0f - 2.0f*RCP(1.0f + EXP2(v)); }

// TRANSPOSED orientation: gates^T = W_ext @ [h; x; 1].
// Block = 128 threads = 2 waves, 16 sequences. Wave w owns units 32w..32w+31.
// Tiles tt = gi*2+d (gi=gate i/f/g/o, d=half): m-tile gi*4+2w+d, unit rows.
// A (static, registers) = W rows; B (per step) = h from LDS, 2x ds_read_b128.
// D layout: col=lane&15 = seq, row=quad*4+r = unit -> lane's 4 outputs are
// CONSECUTIVE units of one seq -> single ds_write_b64 per d-group.
// x-projection: extra MFMA with C=0: A_x = {w_ih,b} @ k=0,1 (quad0 lanes),
// B_x = {x_t, 1} rebuilt in ~2 VALU/step. No per-(tile,r) scalar init fmaf.
// Register demand ~145 combined -> try 3 waves/SIMD (R2: cap128 spilled 24GB;
// R3: cap168 w/ old structure spilled 3GB; this structure is ~25 regs leaner).
__global__ __launch_bounds__(128, 3)
void lstm_fused(const float* __restrict__ x,
                const float* __restrict__ W_ih,
                const float* __restrict__ W_hh,
                const float* __restrict__ b_ih,
                const float* __restrict__ b_hh,
                const float* __restrict__ W_fc,
                const float* __restrict__ b_fc,
                float* __restrict__ out)
{
    __shared__ _Float16 sH[2][16 * HS];    // h double-buffer: h[seq][unit], fp16
    __shared__ float    sXT[SEQ_LEN * 16]; // x tile, transposed [t][seq]

    const int tid  = threadIdx.x;
    const int wave = tid >> 6;
    const int lane = tid & 63;
    const int col  = lane & 15;
    const int quad = lane >> 4;
    const int seqBase = blockIdx.x << 4;

    // ---- stage x transposed: sXT[t*16 + s] = x[(seqBase+s)*50 + t]
    for (int i = tid; i < SEQ_LEN * 16; i += 128) {
        const int s = i & 15;
        const int t = i >> 4;
        sXT[t * 16 + s] = x[(size_t)(seqBase + s) * SEQ_LEN + t];
    }
    // ---- zero both h buffers (h0 = 0)
    for (int i = tid; i < 2 * 16 * HS; i += 128)
        ((_Float16*)sH)[i] = (_Float16)0.0f;

    // ---- W_hh rows as resident fp16 A-fragments, pre-scaled (i,f,o: log2e;
    // g: 2log2e). A[m=col][k=quad*8+j] = W[unit][kf*32+quad*8+j].
    // A_x: {w_ih*scale, b*scale} at k=0,1 — nonzero only for quad 0.
    h8 Aw[8][2];
    h8 Ax[8];
    #pragma unroll
    for (int gi = 0; gi < 4; ++gi) {
        const float scale = (gi == 2) ? LOG2E2 : LOG2E;
        #pragma unroll
        for (int d = 0; d < 2; ++d) {
            const int tt = gi * 2 + d;
            const int n  = (gi * 4 + 2 * wave + d) * 16 + col;
            h8 axf = {};
            if (quad == 0) {
                axf[0] = (_Float16)(W_ih[n] * scale);
                axf[1] = (_Float16)((b_ih[n] + b_hh[n]) * scale);
            }
            Ax[tt] = axf;
            #pragma unroll
            for (int kf = 0; kf < 2; ++kf) {
                const float* wp = W_hh + n * HID + kf * 32 + quad * 8;
                f4 lo = *(const f4*)wp;
                f4 hi = *(const f4*)(wp + 4);
                h8 b;
                b[0] = (_Float16)(lo[0] * scale); b[1] = (_Float16)(lo[1] * scale);
                b[2] = (_Float16)(lo[2] * scale); b[3] = (_Float16)(lo[3] * scale);
                b[4] = (_Float16)(hi[0] * scale); b[5] = (_Float16)(hi[1] * scale);
                b[6] = (_Float16)(hi[2] * scale); b[7] = (_Float16)(hi[3] * scale);
                Aw[tt][kf] = b;
            }
        }
    }

    const f4 z4 = {0.0f, 0.0f, 0.0f, 0.0f};

    // cell state, kept in the 2log2e-scaled domain
    float c[2][4];
    #pragma unroll
    for (int d = 0; d < 2; ++d)
        #pragma unroll
        for (int r = 0; r < 4; ++r) c[d][r] = 0.0f;

    __syncthreads();

    #pragma unroll 2
    for (int t = 0; t < SEQ_LEN; ++t) {
        const _Float16* hb = sH[t & 1];
        _Float16*       hw = sH[(t + 1) & 1];

        // B_x = {x_t[seq], 1, 0...}: only k=0,1 (quad0 lanes of A_x) matter;
        // other quads' values are multiplied by A_x zeros.
        const float xt = sXT[t * 16 + col];
        h8 bx = {};
        bx[0] = (_Float16)xt;
        bx[1] = (_Float16)1.0f;

        // B = h^T fragments: B[k=quad*8+j][n=col] = h[col][kf*32+quad*8+j]
        const h8 Bh0 = *(const h8*)(hb + col * HS + quad * 8);
        const h8 Bh1 = *(const h8*)(hb + col * HS + 32 + quad * 8);

        // Two d-groups: 4 live accumulators each (i,f,g,o of the same units)
        #pragma unroll
        for (int d = 0; d < 2; ++d) {
            f4 acc[4];
            #pragma unroll
            for (int gi = 0; gi < 4; ++gi) {
                const int tt = gi * 2 + d;
                f4 a = __builtin_amdgcn_mfma_f32_16x16x32_f16(Ax[tt], bx, z4, 0, 0, 0);
                a = __builtin_amdgcn_mfma_f32_16x16x32_f16(Aw[tt][0], Bh0, a, 0, 0, 0);
                a = __builtin_amdgcn_mfma_f32_16x16x32_f16(Aw[tt][1], Bh1, a, 0, 0, 0);
                acc[gi] = a;
            }
            // lane's 4 outputs = units 32w+16d+quad*4 + (0..3) of seq=col
            h4 hv;
            #pragma unroll
            for (int r = 0; r < 4; ++r) {
                float ig = sig2(acc[0][r]);
                float fg = sig2(acc[1][r]);
                float gg = tanh2s(acc[2][r]);   // LOG2E2 * tanh
                float og = sig2(acc[3][r]);
                float cc = fmaf(fg, c[d][r], ig * gg);  // scaled-domain cell
                c[d][r] = cc;
                hv[r] = (_Float16)(og * tanh2(cc));
            }
            *(h4*)(hw + col * HS + 32 * wave + 16 * d + quad * 4) = hv;
        }
        __syncthreads();
    }

    // ---- epilogue: final h in sH[0], layout h[seq][unit] stride HS
    if (lane < 24) {
        const int sl = wave * 8 + lane / 3;  // sequence within tile
        const int nc = lane % 3;             // class
        const _Float16* hp = sH[0] + sl * HS;
        float a = b_fc[nc];
        #pragma unroll
        for (int u = 0; u < HID; ++u)
            a = fmaf((float)hp[u], W_fc[nc * HID + u], a);
        out[(size_t)(seqBase + sl) * 3 + nc] = a;
    }
}

extern "C" void kernel_launch(void* const* d_in, const int* in_sizes, int n_in,
                              void* d_out, int out_size, void* d_ws, size_t ws_size,
                              hipStream_t stream) {
    const float* x    = (const float*)d_in[0];
    const float* W_ih = (const float*)d_in[1];
    const float* W_hh = (const float*)d_in[2];
    const float* b_ih = (const float*)d_in[3];
    const float* b_hh = (const float*)d_in[4];
    const float* W_fc = (const float*)d_in[5];
    const float* b_fc = (const float*)d_in[6];
    float* out = (float*)d_out;

    const int nSeq   = in_sizes[0] / SEQ_LEN;  // 512000
    const int blocks = nSeq / 16;              // 32000

    hipLaunchKernelGGL(lstm_fused, dim3(blocks), dim3(128), 0, stream,
                       x, W_ih, W_hh, b_ih, b_hh, W_fc, b_fc, out);
}

// Round 6
// 1790.389 us; speedup vs baseline: 1.5732x; 1.0207x over previous
//
#include <hip/hip_runtime.h>

typedef _Float16 h8 __attribute__((ext_vector_type(8)));
typedef _Float16 h4 __attribute__((ext_vector_type(4)));
typedef float f4 __attribute__((ext_vector_type(4)));

#define SEQ_LEN 50
#define HID 64
#define HS 72  // halves per h row: 144B pitch; 16B-aligned b128 reads

#if __has_builtin(__builtin_amdgcn_exp2f)
#define EXP2(x) __builtin_amdgcn_exp2f(x)
#else
extern "C" __device__ float __ocml_native_exp2_f32(float);
#define EXP2(x) __ocml_native_exp2_f32(x)
#endif
#define RCP(x) __builtin_amdgcn_rcpf(x)

#define LOG2E  1.442695041f
#define LOG2E2 2.885390082f

// TRANSPOSED orientation: gates^T = W_ext @ [h; x; 1].
// Block = 128 threads = 2 waves, 16 sequences. Wave w owns units 32w..32w+31.
// A (static, registers) = W rows; B (per step) = h from LDS, 2x ds_read_b128.
// D layout: col=lane&15 = seq, row=quad*4+r = unit -> lane's 4 outputs are
// consecutive units of one seq -> single ds_write_b64 per d-group.
// x-projection folded into an MFMA with C=0 (A_x nonzero only in quad 0).
//
// Activation math (R6): fused denominators. Gate pre-acts arrive pre-scaled
// (i,f,o rows by log2e; g rows by 2log2e; folded into A at setup). Cell kept
// in the 2log2e-scaled domain.  Ei=2^-ai', Ef=2^-af', Eg=2^g', Eo=2^-ao':
//   c' = [c*pi*pg + L2*(Eg-1)*pf] / (pf*pi*pg)     (1 rcp for i,f,g)
//   h  = (Ec-1) / (po*(Ec+1)),  Ec = 2^c'          (1 rcp for o,tanh)
// => 5 exp2 + 2 rcp = 7 trans/unit (was 10); trans is the 8-cyc bottleneck.
// Clamp c' <= 126 so Ec never overflows to inf (inf*0 -> NaN otherwise).
//
// Register demand ~150 combined -> 3 waves/SIMD fits (R5: VGPR 84, no spill).
__global__ __launch_bounds__(128, 3)
void lstm_fused(const float* __restrict__ x,
                const float* __restrict__ W_ih,
                const float* __restrict__ W_hh,
                const float* __restrict__ b_ih,
                const float* __restrict__ b_hh,
                const float* __restrict__ W_fc,
                const float* __restrict__ b_fc,
                float* __restrict__ out)
{
    __shared__ _Float16 sH[2][16 * HS];    // h double-buffer: h[seq][unit], fp16
    __shared__ float    sXT[SEQ_LEN * 16]; // x tile, transposed [t][seq]

    const int tid  = threadIdx.x;
    const int wave = tid >> 6;
    const int lane = tid & 63;
    const int col  = lane & 15;
    const int quad = lane >> 4;
    const int seqBase = blockIdx.x << 4;

    // ---- stage x transposed: sXT[t*16 + s] = x[(seqBase+s)*50 + t]
    for (int i = tid; i < SEQ_LEN * 16; i += 128) {
        const int s = i & 15;
        const int t = i >> 4;
        sXT[t * 16 + s] = x[(size_t)(seqBase + s) * SEQ_LEN + t];
    }
    // ---- zero both h buffers (h0 = 0)
    for (int i = tid; i < 2 * 16 * HS; i += 128)
        ((_Float16*)sH)[i] = (_Float16)0.0f;

    // ---- W_hh rows as resident fp16 A-fragments, pre-scaled (i,f,o: log2e;
    // g: 2log2e). A[m=col][k=quad*8+j] = W[unit][kf*32+quad*8+j].
    // A_x: {w_ih*scale, b*scale} at k=0,1 — nonzero only for quad 0.
    h8 Aw[8][2];
    h8 Ax[8];
    #pragma unroll
    for (int gi = 0; gi < 4; ++gi) {
        const float scale = (gi == 2) ? LOG2E2 : LOG2E;
        #pragma unroll
        for (int d = 0; d < 2; ++d) {
            const int tt = gi * 2 + d;
            const int n  = (gi * 4 + 2 * wave + d) * 16 + col;
            h8 axf = {};
            if (quad == 0) {
                axf[0] = (_Float16)(W_ih[n] * scale);
                axf[1] = (_Float16)((b_ih[n] + b_hh[n]) * scale);
            }
            Ax[tt] = axf;
            #pragma unroll
            for (int kf = 0; kf < 2; ++kf) {
                const float* wp = W_hh + n * HID + kf * 32 + quad * 8;
                f4 lo = *(const f4*)wp;
                f4 hi = *(const f4*)(wp + 4);
                h8 b;
                b[0] = (_Float16)(lo[0] * scale); b[1] = (_Float16)(lo[1] * scale);
                b[2] = (_Float16)(lo[2] * scale); b[3] = (_Float16)(lo[3] * scale);
                b[4] = (_Float16)(hi[0] * scale); b[5] = (_Float16)(hi[1] * scale);
                b[6] = (_Float16)(hi[2] * scale); b[7] = (_Float16)(hi[3] * scale);
                Aw[tt][kf] = b;
            }
        }
    }

    const f4 z4 = {0.0f, 0.0f, 0.0f, 0.0f};

    // cell state, kept in the 2log2e-scaled domain
    float c[2][4];
    #pragma unroll
    for (int d = 0; d < 2; ++d)
        #pragma unroll
        for (int r = 0; r < 4; ++r) c[d][r] = 0.0f;

    __syncthreads();

    #pragma unroll 2
    for (int t = 0; t < SEQ_LEN; ++t) {
        const _Float16* hb = sH[t & 1];
        _Float16*       hw = sH[(t + 1) & 1];

        // B_x = {x_t[seq], 1, 0...}: only k=0,1 (quad0 lanes of A_x) matter.
        const float xt = sXT[t * 16 + col];
        h8 bx = {};
        bx[0] = (_Float16)xt;
        bx[1] = (_Float16)1.0f;

        // B = h^T fragments: B[k=quad*8+j][n=col] = h[col][kf*32+quad*8+j]
        const h8 Bh0 = *(const h8*)(hb + col * HS + quad * 8);
        const h8 Bh1 = *(const h8*)(hb + col * HS + 32 + quad * 8);

        // Two d-groups: 4 live accumulators each (i,f,g,o of the same units)
        #pragma unroll
        for (int d = 0; d < 2; ++d) {
            f4 acc[4];
            #pragma unroll
            for (int gi = 0; gi < 4; ++gi) {
                const int tt = gi * 2 + d;
                f4 a = __builtin_amdgcn_mfma_f32_16x16x32_f16(Ax[tt], bx, z4, 0, 0, 0);
                a = __builtin_amdgcn_mfma_f32_16x16x32_f16(Aw[tt][0], Bh0, a, 0, 0, 0);
                a = __builtin_amdgcn_mfma_f32_16x16x32_f16(Aw[tt][1], Bh1, a, 0, 0, 0);
                acc[gi] = a;
            }
            // fused-denominator activations: 7 trans + ~15 VALU per unit
            h4 hv;
            #pragma unroll
            for (int r = 0; r < 4; ++r) {
                float Ei = EXP2(-acc[0][r]);
                float Ef = EXP2(-acc[1][r]);
                float Eg = EXP2( acc[2][r]);
                float Eo = EXP2(-acc[3][r]);
                float pi_ = 1.0f + Ei;
                float pf_ = 1.0f + Ef;
                float pg_ = 1.0f + Eg;
                float po_ = 1.0f + Eo;
                float t1  = pi_ * pg_;
                float v   = fmaf(Eg, LOG2E2, -LOG2E2) * pf_;   // L2*(Eg-1)*pf
                float num = fmaf(c[d][r], t1, v);
                float rc  = RCP(pf_ * t1);
                float cn  = fminf(num * rc, 126.0f);           // overflow guard
                c[d][r] = cn;
                float Ec  = EXP2(cn);
                float rh  = RCP(po_ * (1.0f + Ec));
                hv[r] = (_Float16)((Ec - 1.0f) * rh);
            }
            *(h4*)(hw + col * HS + 32 * wave + 16 * d + quad * 4) = hv;
        }
        __syncthreads();
    }

    // ---- epilogue: final h in sH[0], layout h[seq][unit] stride HS
    if (lane < 24) {
        const int sl = wave * 8 + lane / 3;  // sequence within tile
        const int nc = lane % 3;             // class
        const _Float16* hp = sH[0] + sl * HS;
        float a = b_fc[nc];
        #pragma unroll
        for (int u = 0; u < HID; ++u)
            a = fmaf((float)hp[u], W_fc[nc * HID + u], a);
        out[(size_t)(seqBase + sl) * 3 + nc] = a;
    }
}

extern "C" void kernel_launch(void* const* d_in, const int* in_sizes, int n_in,
                              void* d_out, int out_size, void* d_ws, size_t ws_size,
                              hipStream_t stream) {
    const float* x    = (const float*)d_in[0];
    const float* W_ih = (const float*)d_in[1];
    const float* W_hh = (const float*)d_in[2];
    const float* b_ih = (const float*)d_in[3];
    const float* b_hh = (const float*)d_in[4];
    const float* W_fc = (const float*)d_in[5];
    const float* b_fc = (const float*)d_in[6];
    float* out = (float*)d_out;

    const int nSeq   = in_sizes[0] / SEQ_LEN;  // 512000
    const int blocks = nSeq / 16;              // 32000

    hipLaunchKernelGGL(lstm_fused, dim3(blocks), dim3(128), 0, stream,
                       x, W_ih, W_hh, b_ih, b_hh, W_fc, b_fc, out);
}